// Round 18
// baseline (422.031 us; speedup 1.0000x reference)
//
#include <hip/hip_runtime.h>
#include <hip/hip_bf16.h>

// Problem constants
#define Bq   64
#define Tt   512
#define DIN  512
#define Ss   8
#define HSs  128
#define Hh   8
#define Mm   1024
#define KDd  128
#define NGg  2048

typedef __attribute__((ext_vector_type(8))) short bf16x8;
typedef __attribute__((ext_vector_type(4))) float f32x4;

__device__ __forceinline__ ushort f2b(float f) {
    union { float f; unsigned u; } v; v.f = f;
    unsigned r = v.u + 0x7fffu + ((v.u >> 16) & 1u);   // RNE
    return (ushort)(r >> 16);
}
__device__ __forceinline__ float b2f(ushort b) {
    union { unsigned u; float f; } v; v.u = ((unsigned)b) << 16;
    return v.f;
}
__device__ __forceinline__ float blo(unsigned u) {
    union { unsigned u; float f; } v; v.u = u << 16; return v.f;
}
__device__ __forceinline__ float bhi(unsigned u) {
    union { unsigned u; float f; } v; v.u = u & 0xffff0000u; return v.f;
}

#define GLOAD_LDS16(g, l) __builtin_amdgcn_global_load_lds( \
    (const __attribute__((address_space(1))) void*)(g),     \
    (__attribute__((address_space(3))) void*)(l), 16, 0, 0)

#define LGKM0 do { asm volatile("s_waitcnt lgkmcnt(0)" ::: "memory");         \
                   __builtin_amdgcn_sched_barrier(0); } while (0)

// Shared K-loop body for the 256x256 bf16 MFMA GEMM (r12 gray-code schedule).
#define GEMM_BODY(A_, Bt_, Kdim_)                                             \
    const int NT = (Kdim_) >> 6;                                              \
    const int sr = tid >> 3;                                                  \
    const int sq = (tid & 7) ^ (sr & 7);                                      \
    const ushort* Asrc = (A_)  + (size_t)(row0 + sr) * (Kdim_) + sq * 8;      \
    const ushort* Bsrc = (Bt_) + (size_t)(col0 + sr) * (Kdim_) + sq * 8;      \
    const int ldsw = wid * 1024;                                              \
    auto stage = [&](int isB, int U, int h) {                                 \
        const ushort* s = (isB ? Bsrc : Asrc) + (size_t)h * 128 * (Kdim_)     \
                        + (size_t)U * 64;                                     \
        char* d = lds + (isB ? 65536 : 0) + ((((U) & 1) * 2 + h) << 14) + ldsw;\
        GLOAD_LDS16(s, d);                                                    \
        GLOAD_LDS16(s + (size_t)64 * (Kdim_), d + 8192);                      \
    };                                                                        \
    auto stage_tile = [&](int U) {                                            \
        stage(0, U, 0); stage(0, U, 1); stage(1, U, 0); stage(1, U, 1);       \
    };                                                                        \
    const int l15   = lane & 15;                                              \
    const int s0_16 = (((lane >> 4)) ^ (lane & 7)) << 4;                      \
    const int s1_16 = ((4 + (lane >> 4)) ^ (lane & 7)) << 4;                  \
    const int aoff  = wy * 8192 + l15 * 128;                                  \
    const int boff  = wx * 4096 + l15 * 128;                                  \
    f32x4 acc[4][4][2];                                                       \
    _Pragma("unroll")                                                         \
    for (int p = 0; p < 4; ++p)                                               \
        _Pragma("unroll")                                                     \
        for (int m = 0; m < 4; ++m)                                           \
            _Pragma("unroll")                                                 \
            for (int n = 0; n < 2; ++n) acc[p][m][n] = (f32x4){0.f,0.f,0.f,0.f};\
    stage_tile(0);                                                            \
    stage_tile(1);                                                            \
    asm volatile("s_waitcnt vmcnt(8)" ::: "memory");                          \
    __builtin_amdgcn_s_barrier();                                             \
    asm volatile("" ::: "memory");                                            \
    for (int U = 0; U < NT; ++U) {                                            \
        const char* Ab = lds + ((U & 1) << 15);                               \
        const char* Bb = lds + 65536 + ((U & 1) << 15);                       \
        bf16x8 a0[2][4], a1[2][4];                                            \
        bf16x8 b0[2][2], b1[2][2];                                            \
        _Pragma("unroll")                                                     \
        for (int m = 0; m < 4; ++m) {                                         \
            a0[0][m] = *(const bf16x8*)(Ab + aoff + s0_16 + m * 2048);        \
            a0[1][m] = *(const bf16x8*)(Ab + aoff + s1_16 + m * 2048);        \
        }                                                                     \
        _Pragma("unroll")                                                     \
        for (int n = 0; n < 2; ++n) {                                         \
            b0[0][n] = *(const bf16x8*)(Bb + boff + s0_16 + n * 2048);        \
            b0[1][n] = *(const bf16x8*)(Bb + boff + s1_16 + n * 2048);        \
        }                                                                     \
        LGKM0;                                                                \
        _Pragma("unroll")                                                     \
        for (int m = 0; m < 4; ++m) {                                         \
            a1[0][m] = *(const bf16x8*)(Ab + 16384 + aoff + s0_16 + m * 2048);\
            a1[1][m] = *(const bf16x8*)(Ab + 16384 + aoff + s1_16 + m * 2048);\
        }                                                                     \
        MFMAQ(0, a0, b0);                                                     \
        LGKM0;                                                                \
        _Pragma("unroll")                                                     \
        for (int n = 0; n < 2; ++n) {                                         \
            b1[0][n] = *(const bf16x8*)(Bb + 16384 + boff + s0_16 + n * 2048);\
            b1[1][n] = *(const bf16x8*)(Bb + 16384 + boff + s1_16 + n * 2048);\
        }                                                                     \
        MFMAQ(1, a1, b0);                                                     \
        LGKM0;                                                                \
        __builtin_amdgcn_s_barrier();                                         \
        asm volatile("" ::: "memory");                                        \
        if (U + 2 < NT) stage_tile(U + 2);                                    \
        MFMAQ(3, a1, b1);                                                     \
        MFMAQ(2, a0, b1);                                                     \
        if (U + 2 < NT) asm volatile("s_waitcnt vmcnt(8)" ::: "memory");      \
        else            asm volatile("s_waitcnt vmcnt(0)" ::: "memory");      \
        __builtin_amdgcn_s_barrier();                                         \
        asm volatile("" ::: "memory");                                        \
    }

#define MFMAQ(P, AH, BH)                                                      \
    {                                                                         \
        __builtin_amdgcn_s_setprio(1);                                        \
        _Pragma("unroll")                                                     \
        for (int kk = 0; kk < 2; ++kk)                                        \
            _Pragma("unroll")                                                 \
            for (int m = 0; m < 4; ++m)                                       \
                _Pragma("unroll")                                             \
                for (int n = 0; n < 2; ++n)                                   \
                    acc[P][m][n] = __builtin_amdgcn_mfma_f32_16x16x32_bf16(   \
                        AH[kk][m], BH[kk][n], acc[P][m][n], 0, 0, 0);         \
        __builtin_amdgcn_s_setprio(0);                                        \
    }

// ---------------------------------------------------------------------------
// 256x256 bf16 MFMA GEMM (r12 schedule), standard C epilogue.
// ---------------------------------------------------------------------------
template<int OUT_BF16>
__global__ __launch_bounds__(512)
void gemm_big(const ushort* __restrict__ A, const ushort* __restrict__ Bt,
              const float* __restrict__ bias, void* __restrict__ Cout,
              int ldc, int Kdim)
{
    extern __shared__ __align__(16) char lds[];   // 131072 bytes

    const int tid  = threadIdx.x;
    const int wid  = tid >> 6;
    const int lane = tid & 63;
    const int wy   = wid >> 2;
    const int wx   = wid & 3;

    const int gx   = gridDim.x;
    const int nwg  = gx * gridDim.y;
    const int orig = blockIdx.y * gx + blockIdx.x;
    const int q8   = nwg >> 3, r8 = nwg & 7;
    const int xcd  = orig & 7, idx8 = orig >> 3;
    const int swz  = (xcd < r8 ? xcd * (q8 + 1)
                               : r8 * (q8 + 1) + (xcd - r8) * q8) + idx8;
    const int row0 = (swz / gx) * 256;
    const int col0 = (swz % gx) * 256;

    GEMM_BODY(A, Bt, Kdim)

#pragma unroll
    for (int p = 0; p < 4; ++p) {
        const int rb = row0 + (p & 1) * 128 + wy * 64 + (lane >> 4) * 4;
        const int cb = col0 + (p >> 1) * 128 + wx * 32 + (lane & 15);
#pragma unroll
        for (int n = 0; n < 2; ++n) {
            const float bv = bias[cb + n * 16];
#pragma unroll
            for (int m = 0; m < 4; ++m) {
#pragma unroll
                for (int r = 0; r < 4; ++r) {
                    const float v = acc[p][m][n][r] + bv;
                    const size_t off = (size_t)(rb + m * 16 + r) * ldc + cb + n * 16;
                    if (OUT_BF16) ((ushort*)Cout)[off] = f2b(v);
                    else          ((float*)Cout)[off]  = v;
                }
            }
        }
    }
}

// ---------------------------------------------------------------------------
// gemm_gi: same K-loop; epilogue computes column sums of relu(rl_w*(acc+bp))
// over the block's 256 rows -> partial[row0/256][col]. Deterministic.
// ---------------------------------------------------------------------------
__global__ __launch_bounds__(512)
void gemm_gi(const ushort* __restrict__ A, const ushort* __restrict__ Bt,
             const float* __restrict__ bp, const float* __restrict__ rl_w,
             float* __restrict__ partial, int Kdim)
{
    extern __shared__ __align__(16) char lds[];   // 131072 bytes

    const int tid  = threadIdx.x;
    const int wid  = tid >> 6;
    const int lane = tid & 63;
    const int wy   = wid >> 2;
    const int wx   = wid & 3;

    const int gx   = gridDim.x;
    const int nwg  = gx * gridDim.y;
    const int orig = blockIdx.y * gx + blockIdx.x;
    const int q8   = nwg >> 3, r8 = nwg & 7;
    const int xcd  = orig & 7, idx8 = orig >> 3;
    const int swz  = (xcd < r8 ? xcd * (q8 + 1)
                               : r8 * (q8 + 1) + (xcd - r8) * q8) + idx8;
    const int row0 = (swz / gx) * 256;
    const int col0 = (swz % gx) * 256;

    GEMM_BODY(A, Bt, Kdim)

    float csum[2][2];
#pragma unroll
    for (int ph = 0; ph < 2; ++ph) {
#pragma unroll
        for (int n = 0; n < 2; ++n) {
            const int col = col0 + ph * 128 + wx * 32 + n * 16 + (lane & 15);
            const float bb = bp[col];
            const float w  = rl_w[col];
            float s = 0.f;
#pragma unroll
            for (int rh = 0; rh < 2; ++rh) {
                const int p = ph * 2 + rh;
#pragma unroll
                for (int m = 0; m < 4; ++m)
#pragma unroll
                    for (int r = 0; r < 4; ++r)
                        s += fmaxf(w * (acc[p][m][n][r] + bb), 0.f);
            }
            s += __shfl_xor(s, 16);
            s += __shfl_xor(s, 32);
            csum[ph][n] = s;
        }
    }
    float* redf = (float*)lds;          // [2 wy][256 localcol]
    if ((lane >> 4) == 0) {
#pragma unroll
        for (int ph = 0; ph < 2; ++ph)
#pragma unroll
            for (int n = 0; n < 2; ++n)
                redf[wy * 256 + ph * 128 + wx * 32 + n * 16 + lane] = csum[ph][n];
    }
    __syncthreads();
    if (tid < 256)
        partial[(size_t)(row0 >> 8) * Mm + col0 + tid] = redf[tid] + redf[256 + tid];
}

// gi_finalize: gimean16[b_local][m] = bf16((partial[2b][m]+partial[2b+1][m])/T)
__global__ __launch_bounds__(256)
void gi_finalize(const float* __restrict__ partial, ushort* __restrict__ gimean16)
{
    const int i = blockIdx.x * 256 + threadIdx.x;   // over Bc*Mm
    const int bl = i >> 10, m = i & (Mm - 1);
    const float v = (partial[(size_t)(2 * bl) * Mm + m]
                   + partial[(size_t)(2 * bl + 1) * Mm + m]) * (1.f / (float)Tt);
    gimean16[i] = f2b(v);
}

// ---------------------------------------------------------------------------
// Small 128x128 bf16 MFMA GEMM: BK=32, 4 waves, 64x64/wave, 16 KB LDS.
// ---------------------------------------------------------------------------
template<int OUT_BF16, int RELU>
__global__ __launch_bounds__(256)
void gemm_sm(const ushort* __restrict__ A, const ushort* __restrict__ Bt,
             const float* __restrict__ bias, void* __restrict__ Cout,
             int ldc, int Kdim)
{
    __shared__ __align__(16) ushort As[128 * 32];   // 8 KB
    __shared__ __align__(16) ushort Bs[128 * 32];   // 8 KB

    const int tid  = threadIdx.x;
    const int w    = tid >> 6;
    const int lane = tid & 63;

    const int gx   = gridDim.x;
    const int nwg  = gx * gridDim.y;
    const int orig = blockIdx.y * gx + blockIdx.x;
    const int q8   = nwg >> 3, r8 = nwg & 7;
    const int xcd  = orig & 7, idx8 = orig >> 3;
    const int swz  = (xcd < r8 ? xcd * (q8 + 1)
                               : r8 * (q8 + 1) + (xcd - r8) * q8) + idx8;
    const int row0 = (swz / gx) * 128;
    const int col0 = (swz % gx) * 128;
    const int wr   = w >> 1, wc = w & 1;

    f32x4 acc[4][4];
#pragma unroll
    for (int i = 0; i < 4; ++i)
#pragma unroll
        for (int j = 0; j < 4; ++j) acc[i][j] = (f32x4){0.f, 0.f, 0.f, 0.f};

    const ushort* Ag = A  + (size_t)(row0 + (tid >> 2)) * Kdim + (tid & 3) * 8;
    const ushort* Bg = Bt + (size_t)(col0 + (tid >> 2)) * Kdim + (tid & 3) * 8;

    for (int k0 = 0; k0 < Kdim; k0 += 32) {
        __syncthreads();
#pragma unroll
        for (int is = 0; is < 2; ++is)
            GLOAD_LDS16(Ag + (size_t)is * 64 * Kdim + k0,
                        (char*)As + (is * 256 + w * 64) * 16);
#pragma unroll
        for (int is = 0; is < 2; ++is)
            GLOAD_LDS16(Bg + (size_t)is * 64 * Kdim + k0,
                        (char*)Bs + (is * 256 + w * 64) * 16);
        asm volatile("s_waitcnt vmcnt(0)" ::: "memory");
        __syncthreads();

        bf16x8 a[4], b[4];
#pragma unroll
        for (int i = 0; i < 4; ++i) {
            a[i] = *(const bf16x8*)&As[(wr * 64 + i * 16 + (lane & 15)) * 32 + (lane >> 4) * 8];
            b[i] = *(const bf16x8*)&Bs[(wc * 64 + i * 16 + (lane & 15)) * 32 + (lane >> 4) * 8];
        }
#pragma unroll
        for (int i = 0; i < 4; ++i)
#pragma unroll
            for (int j = 0; j < 4; ++j)
                acc[i][j] = __builtin_amdgcn_mfma_f32_16x16x32_bf16(a[i], b[j], acc[i][j], 0, 0, 0);
    }

    float bsv[4];
#pragma unroll
    for (int j = 0; j < 4; ++j) bsv[j] = bias[col0 + wc * 64 + j * 16 + (lane & 15)];
#pragma unroll
    for (int i = 0; i < 4; ++i) {
        const int row = row0 + wr * 64 + i * 16 + (lane >> 4) * 4;
        const int col = col0 + wc * 64 + (lane & 15);
#pragma unroll
        for (int r = 0; r < 4; ++r) {
            const size_t off = (size_t)(row + r) * ldc + col;
#pragma unroll
            for (int j = 0; j < 4; ++j) {
                float vv = acc[i][j][r] + bsv[j];
                if (RELU) vv = fmaxf(vv, 0.f);
                if (OUT_BF16) ((ushort*)Cout)[off + j * 16] = f2b(vv);
                else          ((float*)Cout)[off + j * 16]  = vv;
            }
        }
    }
}

// ---------------------------------------------------------------------------
// gm_direct: gm[b][s][n] = tanh16[b][s][:] @ gl_W[s][:][n] + gl_b[s][n]
// ---------------------------------------------------------------------------
__global__ __launch_bounds__(256)
void gm_direct(const ushort* __restrict__ tanhA, const float* __restrict__ glW,
               const float* __restrict__ gl_b, float* __restrict__ gm)
{
    const int tid  = threadIdx.x;
    const int w    = tid >> 6;
    const int lane = tid & 63;
    const int s    = blockIdx.y;
    const int n    = blockIdx.x * 64 + w * 16 + (lane & 15);
    const int q8   = (lane >> 4) * 8;

    const float* Bp = glW + (size_t)s * Mm * NGg + n;

    f32x4 acc[4];
#pragma unroll
    for (int i = 0; i < 4; ++i) acc[i] = (f32x4){0.f, 0.f, 0.f, 0.f};

#pragma unroll 2
    for (int k0 = 0; k0 < Mm; k0 += 32) {
        bf16x8 a[4];
#pragma unroll
        for (int i = 0; i < 4; ++i)
            a[i] = *(const bf16x8*)&tanhA[((size_t)(i * 16 + (lane & 15)) * Ss + s) * Mm + k0 + q8];
        bf16x8 bv;
#pragma unroll
        for (int j = 0; j < 8; ++j)
            bv[j] = (short)f2b(Bp[(size_t)(k0 + q8 + j) * NGg]);
#pragma unroll
        for (int i = 0; i < 4; ++i)
            acc[i] = __builtin_amdgcn_mfma_f32_16x16x32_bf16(a[i], bv, acc[i], 0, 0, 0);
    }

    const float bb = gl_b[s * NGg + n];
#pragma unroll
    for (int i = 0; i < 4; ++i) {
#pragma unroll
        for (int r = 0; r < 4; ++r) {
            const int b = i * 16 + (lane >> 4) * 4 + r;
            gm[((size_t)b * Ss + s) * NGg + n] = acc[i][r] + bb;
        }
    }
}

// ---------------------------------------------------------------------------
// gi_direct: gi[b][n] = gimean16[b][:] @ rl_W[:][n] + rl_b[n]  (64 rows)
// Same structure as gm_direct, no s dimension. Grid (NGg/64) = 32 blocks.
// ---------------------------------------------------------------------------
__global__ __launch_bounds__(256)
void gi_direct(const ushort* __restrict__ giA, const float* __restrict__ rlW,
               const float* __restrict__ rl_b, float* __restrict__ gi)
{
    const int tid  = threadIdx.x;
    const int w    = tid >> 6;
    const int lane = tid & 63;
    const int n    = blockIdx.x * 64 + w * 16 + (lane & 15);
    const int q8   = (lane >> 4) * 8;

    const float* Bp = rlW + n;

    f32x4 acc[4];
#pragma unroll
    for (int i = 0; i < 4; ++i) acc[i] = (f32x4){0.f, 0.f, 0.f, 0.f};

#pragma unroll 2
    for (int k0 = 0; k0 < Mm; k0 += 32) {
        bf16x8 a[4];
#pragma unroll
        for (int i = 0; i < 4; ++i)
            a[i] = *(const bf16x8*)&giA[(size_t)(i * 16 + (lane & 15)) * Mm + k0 + q8];
        bf16x8 bv;
#pragma unroll
        for (int j = 0; j < 8; ++j)
            bv[j] = (short)f2b(Bp[(size_t)(k0 + q8 + j) * NGg]);
#pragma unroll
        for (int i = 0; i < 4; ++i)
            acc[i] = __builtin_amdgcn_mfma_f32_16x16x32_bf16(a[i], bv, acc[i], 0, 0, 0);
    }

    const float bb = rl_b[n];
#pragma unroll
    for (int i = 0; i < 4; ++i) {
#pragma unroll
        for (int r = 0; r < 4; ++r) {
            const int b = i * 16 + (lane >> 4) * 4 + r;
            gi[(size_t)b * NGg + n] = acc[i][r] + bb;
        }
    }
}

// ---------------------------------------------------------------------------
__global__ __launch_bounds__(256)
void transpose_to_bf16(const float* __restrict__ in, ushort* __restrict__ out,
                       int R, int C)
{
    __shared__ float t[32][33];
    const int c0 = blockIdx.x * 32, r0 = blockIdx.y * 32;
    const int tx = threadIdx.x & 31, ty = threadIdx.x >> 5;   // 32 x 8
#pragma unroll
    for (int i = 0; i < 32; i += 8)
        t[ty + i][tx] = in[(size_t)(r0 + ty + i) * C + c0 + tx];
    __syncthreads();
#pragma unroll
    for (int i = 0; i < 32; i += 8)
        out[(size_t)(c0 + ty + i) * R + r0 + tx] = f2b(t[tx][ty + i]);
}

// 4x 1024x1024 transposes in one launch (blockIdx.z selects the matrix)
__global__ __launch_bounds__(256)
void transpose4_to_bf16(const float* __restrict__ s0, const float* __restrict__ s1,
                        const float* __restrict__ s2, const float* __restrict__ s3,
                        ushort* __restrict__ d0, ushort* __restrict__ d1,
                        ushort* __restrict__ d2, ushort* __restrict__ d3)
{
    const float* in; ushort* out;
    switch (blockIdx.z) {
        case 0:  in = s0; out = d0; break;
        case 1:  in = s1; out = d1; break;
        case 2:  in = s2; out = d2; break;
        default: in = s3; out = d3; break;
    }
    __shared__ float t[32][33];
    const int c0 = blockIdx.x * 32, r0 = blockIdx.y * 32;
    const int tx = threadIdx.x & 31, ty = threadIdx.x >> 5;
#pragma unroll
    for (int i = 0; i < 32; i += 8)
        t[ty + i][tx] = in[(size_t)(r0 + ty + i) * Mm + c0 + tx];
    __syncthreads();
#pragma unroll
    for (int i = 0; i < 32; i += 8)
        out[(size_t)(c0 + ty + i) * Mm + r0 + tx] = f2b(t[tx][ty + i]);
}

__global__ __launch_bounds__(256)
void conv_bf16(const float* __restrict__ in, ushort* __restrict__ out)
{
    const int i = blockIdx.x * 256 + threadIdx.x;
    float4 v = ((const float4*)in)[i];
    ushort4 o;
    o.x = f2b(v.x); o.y = f2b(v.y); o.z = f2b(v.z); o.w = f2b(v.w);
    ((ushort4*)out)[i] = o;
}

// memory -> bf16(memory) and bf16(tanh(memory)) in one pass
__global__ __launch_bounds__(256)
void mem_tanh_bf16(const float* __restrict__ in, ushort* __restrict__ o1,
                   ushort* __restrict__ o2)
{
    const int i = blockIdx.x * 256 + threadIdx.x;
    float4 v = ((const float4*)in)[i];
    ushort4 a, b;
    a.x = f2b(v.x); a.y = f2b(v.y); a.z = f2b(v.z); a.w = f2b(v.w);
    b.x = f2b(tanhf(v.x)); b.y = f2b(tanhf(v.y));
    b.z = f2b(tanhf(v.z)); b.w = f2b(tanhf(v.w));
    ((ushort4*)o1)[i] = a;
    ((ushort4*)o2)[i] = b;
}

__global__ __launch_bounds__(256)
void fill0(float* __restrict__ o)
{
    o[blockIdx.x * 256 + threadIdx.x] = 0.f;
}

// ---------------------------------------------------------------------------
// fuse_bias: outb[n] = sum_m bp[m] * Wkv[m][n] + bkv[n], n in [0, 2048).
// ---------------------------------------------------------------------------
__global__ __launch_bounds__(256)
void fuse_bias(const float* __restrict__ bp,
               const float* __restrict__ Wk, const float* __restrict__ Wv,
               const float* __restrict__ bk, const float* __restrict__ bv,
               float* __restrict__ outb)
{
    __shared__ float red[4][64];
    const int col = threadIdx.x & 63;
    const int mq  = threadIdx.x >> 6;
    const int n   = blockIdx.x * 64 + col;
    const float* W = (n < Mm) ? Wk : Wv;
    const int nn   = n & (Mm - 1);
    float s = 0.f;
    for (int m = mq * 256; m < mq * 256 + 256; ++m)
        s += bp[m] * W[(size_t)m * Mm + nn];
    red[mq][col] = s;
    __syncthreads();
    if (mq == 0) {
        float t = red[0][col] + red[1][col] + red[2][col] + red[3][col];
        outb[n] = t + ((n < Mm) ? bk[nn] : bv[nn]);
    }
}

// ---------------------------------------------------------------------------
// Fused attention per (b, h), 512 threads (8 waves). q fp32; kv bf16 [.,T,2M].
// ---------------------------------------------------------------------------
__global__ __launch_bounds__(512)
void attn_kernel(const float* __restrict__ q, const ushort* __restrict__ kv,
                 float* __restrict__ att)
{
    const int b = blockIdx.x / Hh;
    const int h = blockIdx.x % Hh;
    const int tid = threadIdx.x;

    __shared__ float qs[Ss][KDd];     // 4 KB
    __shared__ float sc[Ss][Tt];      // 16 KB

    {
        const int idx = tid * 2;
        const int s = idx >> 7;
        const int d = idx & 127;
        float2 qv = *(const float2*)&q[((size_t)(b * Ss + s)) * Mm + h * KDd + d];
        qs[s][d] = qv.x; qs[s][d + 1] = qv.y;
    }
    __syncthreads();

    {
        const int t = tid;
        const ushort* kr = kv + ((size_t)(b * Tt + t)) * (2 * Mm) + h * KDd;
        float acc[Ss];
#pragma unroll
        for (int s = 0; s < Ss; ++s) acc[s] = 0.f;
        for (int d = 0; d < KDd; d += 8) {
            uint4 u = *(const uint4*)(kr + d);
            float k0 = blo(u.x), k1 = bhi(u.x), k2 = blo(u.y), k3 = bhi(u.y);
            float k4 = blo(u.z), k5 = bhi(u.z), k6 = blo(u.w), k7 = bhi(u.w);
#pragma unroll
            for (int s = 0; s < Ss; ++s)
                acc[s] += qs[s][d + 0] * k0 + qs[s][d + 1] * k1
                        + qs[s][d + 2] * k2 + qs[s][d + 3] * k3
                        + qs[s][d + 4] * k4 + qs[s][d + 5] * k5
                        + qs[s][d + 6] * k6 + qs[s][d + 7] * k7;
        }
#pragma unroll
        for (int s = 0; s < Ss; ++s) sc[s][t] = acc[s];
    }
    __syncthreads();

    const int s    = tid >> 6;
    const int lane = tid & 63;
    float mx = -1e30f;
    for (int t = lane; t < Tt; t += 64) mx = fmaxf(mx, sc[s][t]);
#pragma unroll
    for (int m = 32; m >= 1; m >>= 1) mx = fmaxf(mx, __shfl_xor(mx, m));
    float sum = 0.f;
    for (int t = lane; t < Tt; t += 64) {
        float e = __expf(sc[s][t] - mx);
        sc[s][t] = e;
        sum += e;
    }
#pragma unroll
    for (int m = 32; m >= 1; m >>= 1) sum += __shfl_xor(sum, m);
    const float inv = 1.f / sum;

    const int d0 = lane * 2;
    const ushort* vb = kv + ((size_t)(b * Tt)) * (2 * Mm) + Mm + h * KDd + d0;
    float ax = 0.f, ay = 0.f;
    for (int t = 0; t < Tt; ++t) {
        const float p = sc[s][t];
        const unsigned u = *(const unsigned*)(vb + (size_t)t * (2 * Mm));
        ax = fmaf(p, blo(u), ax);
        ay = fmaf(p, bhi(u), ay);
    }
    float2 o = make_float2(ax * inv, ay * inv);
    *(float2*)&att[((size_t)(b * Ss + s)) * Mm + h * KDd + d0] = o;
}

// ---------------------------------------------------------------------------
__global__ __launch_bounds__(256)
void ln_add(const float* __restrict__ a, const float* __restrict__ b,
            const float* __restrict__ g, const float* __restrict__ be,
            float* __restrict__ out)
{
    const int row = blockIdx.x;
    const int tid = threadIdx.x;
    const float* ap = a + (size_t)row * Mm;
    const float* bp = b + (size_t)row * Mm;

    float4 av = *(const float4*)&ap[tid * 4];
    float4 bv = *(const float4*)&bp[tid * 4];
    float x0 = av.x + bv.x, x1 = av.y + bv.y, x2 = av.z + bv.z, x3 = av.w + bv.w;
    float s  = x0 + x1 + x2 + x3;
    float ss = x0 * x0 + x1 * x1 + x2 * x2 + x3 * x3;
#pragma unroll
    for (int m = 32; m >= 1; m >>= 1) {
        s  += __shfl_xor(s, m);
        ss += __shfl_xor(ss, m);
    }
    __shared__ float red[2][4];
    const int wid = tid >> 6;
    if ((tid & 63) == 0) { red[0][wid] = s; red[1][wid] = ss; }
    __syncthreads();
    s  = red[0][0] + red[0][1] + red[0][2] + red[0][3];
    ss = red[1][0] + red[1][1] + red[1][2] + red[1][3];
    const float mu  = s * (1.f / (float)Mm);
    const float var = ss * (1.f / (float)Mm) - mu * mu;
    const float inv = rsqrtf(var + 1e-5f);

    float4 gv = *(const float4*)&g[tid * 4];
    float4 bev = *(const float4*)&be[tid * 4];
    float4 o;
    o.x = (x0 - mu) * inv * gv.x + bev.x;
    o.y = (x1 - mu) * inv * gv.y + bev.y;
    o.z = (x2 - mu) * inv * gv.z + bev.z;
    o.w = (x3 - mu) * inv * gv.w + bev.w;
    *(float4*)&out[(size_t)row * Mm + tid * 4] = o;
}

__global__ __launch_bounds__(256)
void combine_kernel(const float* __restrict__ gm, const float* __restrict__ gi,
                    const float* __restrict__ nextm, const float* __restrict__ memory,
                    const float* __restrict__ ibp, const float* __restrict__ fbp,
                    float* __restrict__ out)
{
    const int idx = blockIdx.x * 256 + threadIdx.x;
    const int m  = idx & (Mm - 1);
    const int bs = idx >> 10;
    const int b  = bs >> 3;
    const float ib = ibp[0], fb = fbp[0];
    const float gmi = gm[(size_t)bs * NGg + m];
    const float gmf = gm[(size_t)bs * NGg + Mm + m];
    const float gii = gi[(size_t)b * NGg + m];
    const float gif = gi[(size_t)b * NGg + Mm + m];
    const float ig = 1.f / (1.f + __expf(-(gmi + gii + ib)));
    const float fg = 1.f / (1.f + __expf(-(gmf + gif + fb)));
    out[idx] = ig * tanhf(nextm[idx]) + fg * memory[idx];
}

// ---------------------------------------------------------------------------
extern "C" void kernel_launch(void* const* d_in, const int* in_sizes, int n_in,
                              void* d_out, int out_size, void* d_ws, size_t ws_size,
                              hipStream_t stream)
{
    const float* inputs = (const float*)d_in[0];
    const float* memory = (const float*)d_in[1];
    const float* Wp  = (const float*)d_in[2];
    const float* bp  = (const float*)d_in[3];
    const float* Wq  = (const float*)d_in[4];
    const float* bq  = (const float*)d_in[5];
    const float* Wk  = (const float*)d_in[6];
    const float* bk  = (const float*)d_in[7];
    const float* Wv  = (const float*)d_in[8];
    const float* bv  = (const float*)d_in[9];
    const float* Wm  = (const float*)d_in[10];
    const float* bm  = (const float*)d_in[11];
    const float* g1  = (const float*)d_in[12];
    const float* be1 = (const float*)d_in[13];
    const float* g2  = (const float*)d_in[14];
    const float* be2 = (const float*)d_in[15];
    const float* rl_w = (const float*)d_in[16];
    const float* rl_W = (const float*)d_in[17];
    const float* rl_b = (const float*)d_in[18];
    const float* gl_W = (const float*)d_in[19];
    const float* gl_b = (const float*)d_in[20];
    const float* ibp  = (const float*)d_in[21];
    const float* fbp  = (const float*)d_in[22];
    float* out = (float*)d_out;

    // allow 128 KiB dynamic LDS for the big MFMA GEMMs
    (void)hipFuncSetAttribute(reinterpret_cast<const void*>(&gemm_big<1>),
                              hipFuncAttributeMaxDynamicSharedMemorySize, 131072);
    (void)hipFuncSetAttribute(reinterpret_cast<const void*>(&gemm_gi),
                              hipFuncAttributeMaxDynamicSharedMemorySize, 131072);

    // ---- workspace layout (float units) ----
    const size_t N_SM = (size_t)Bq * Ss * Mm;     // 524,288
    float* ws = (float*)d_ws;
    float* qbuf   = ws;
    float* attb   = qbuf   + N_SM;
    float* mem1   = attb   + N_SM;
    float* mlp2   = mem1   + N_SM;
    float* nextm  = mlp2   + N_SM;
    float* gibuf  = nextm  + N_SM;                        // [64][NGg]
    float* gmbuf  = gibuf  + (size_t)Bq * NGg;
    float* gipart = gmbuf  + (size_t)Bq * Ss * NGg;       // [<=128][Mm] partials
    float* bkvf   = gipart + (size_t)128 * Mm;            // [2048] fused bias
    float* bz     = bkvf + NGg;                           // [512] zeros
    float* pconst = bz + 512;
    // bf16 constants + small bf16 activations
    ushort* ib16  = (ushort*)pconst;                      // [B*T][DIN]
    ushort* WpT   = ib16  + (size_t)Bq * Tt * DIN;        // [M][DIN]
    ushort* WkvT  = WpT   + (size_t)Mm * DIN;             // [2M][M]
    ushort* WqT   = WkvT  + (size_t)2 * Mm * Mm;          // [M][M]
    ushort* WmT   = WqT   + (size_t)Mm * Mm;              // [M][M]
    ushort* mem16 = WmT   + (size_t)Mm * Mm;              // [B*S][M]
    ushort* m116  = mem16 + N_SM;                         // bf16(mem1)
    ushort* mlp116= m116  + N_SM;                         // bf16(relu(mlp1))
    ushort* Wp16  = mlp116 + N_SM;                        // [DIN][M] bf16(Wp)
    ushort* WpkvT = Wp16  + (size_t)DIN * Mm;             // [2M][DIN]
    ushort* tanh16= WpkvT + (size_t)2 * Mm * DIN;         // [B*S][M]
    ushort* gim16 = tanh16 + N_SM;                        // [64][M] bf16(gi_mean)
    ushort* cend  = gim16 + (size_t)Bq * Mm;
    // chunk region start (float*, 16B aligned)
    size_t const_u16 = (size_t)(cend - (ushort*)pconst);
    size_t const_floats = (size_t)(pconst - ws) + (const_u16 + 1) / 2;
    const_floats = (const_floats + 3) & ~(size_t)3;       // 16B align
    float* cstart = ws + const_floats;

    // per-chunk: kv bf16 only ([Bc*T][2M] u16 = Bc*Tt*Mm floats)
    int Bc = Bq;
    while (Bc > 1 &&
           (const_floats + (size_t)Bc * Tt * Mm) * sizeof(float) > ws_size)
        Bc >>= 1;
    ushort* kvb16 = (ushort*)cstart;                      // [Bc*T][2M]

    const dim3 blk(256);

    // ---- precompute bf16 operands + fused weights/bias ----
    conv_bf16<<<dim3((Bq * Tt * DIN) / 1024), blk, 0, stream>>>(inputs, ib16);
    mem_tanh_bf16<<<dim3((Bq * Ss * Mm) / 1024), blk, 0, stream>>>(memory, mem16, tanh16);
    conv_bf16<<<dim3((DIN * Mm) / 1024), blk, 0, stream>>>(Wp, Wp16);
    transpose_to_bf16<<<dim3(Mm / 32, DIN / 32), blk, 0, stream>>>(Wp, WpT, DIN, Mm);
    transpose4_to_bf16<<<dim3(Mm / 32, Mm / 32, 4), blk, 0, stream>>>(
        Wk, Wv, Wq, Wm, WkvT, WkvT + (size_t)Mm * Mm, WqT, WmT);
    fill0<<<dim3(2), blk, 0, stream>>>(bz);

    // WpkvT[n][d] = sum_m WkvT[n][m] * Wp16[d][m]  (= (Wp@Wkv)^T, bf16)
    gemm_sm<1,0><<<dim3(DIN/128, (2*Mm)/128), blk, 0, stream>>>(
        WkvT, Wp16, bz, WpkvT, DIN, Mm);

    // bkvf[n] = bp @ Wkv[:,n] + [bk|bv][n]   (fp32, deterministic)
    fuse_bias<<<dim3(NGg / 64), blk, 0, stream>>>(bp, Wk, Wv, bk, bv, bkvf);

    // q = memory @ Wq + bq   (128^2 MFMA, fp32 out)
    gemm_sm<0,0><<<dim3(Mm/128, (Bq*Ss)/128), blk, 0, stream>>>(
        mem16, WqT, bq, qbuf, Mm, Mm);

    // ---- chunked: kv (fused, K=512), gi (fused epilogue), attention ----
    for (int c0 = 0; c0 < Bq; c0 += Bc) {
        const int rows = Bc * Tt;

        // kv = bf16(inputs_c @ Wpkv + bkvf)   (N=2048, K=512)
        gemm_big<1><<<dim3((2*Mm)/256, rows/256), dim3(512), 131072, stream>>>(
            ib16 + (size_t)c0 * Tt * DIN, WpkvT, bkvf, kvb16, 2*Mm, DIN);

        // gi partials: column sums of relu(rl_w*(inputs_c@Wp + bp))
        gemm_gi<<<dim3(Mm/256, rows/256), dim3(512), 131072, stream>>>(
            ib16 + (size_t)c0 * Tt * DIN, WpT, bp, rl_w, gipart, DIN);
        gi_finalize<<<dim3((Bc * Mm) / 256), blk, 0, stream>>>(
            gipart, gim16 + (size_t)c0 * Mm);

        // attention for this chunk (512-thread blocks)
        attn_kernel<<<dim3(Bc * Hh), dim3(512), 0, stream>>>(
            qbuf + (size_t)c0 * Ss * Mm, kvb16,
            attb + (size_t)c0 * Ss * Mm);
    }

    // mem1 = LN(memory + att) ; then bf16 copy for the MLP GEMMs
    ln_add<<<dim3(Bq * Ss), blk, 0, stream>>>(memory, attb, g1, be1, mem1);
    conv_bf16<<<dim3((Bq * Ss * Mm) / 1024), blk, 0, stream>>>(mem1, m116);

    // mlp1 = relu(mem1 @ Wm + bm)  -> bf16 ; mlp2 = relu(mlp1 @ Wm + bm) -> fp32
    gemm_sm<1,1><<<dim3(Mm/128, (Bq*Ss)/128), blk, 0, stream>>>(
        m116, WmT, bm, mlp116, Mm, Mm);
    gemm_sm<0,1><<<dim3(Mm/128, (Bq*Ss)/128), blk, 0, stream>>>(
        mlp116, WmT, bm, mlp2, Mm, Mm);

    // next = LN(mem1 + mlp2)
    ln_add<<<dim3(Bq * Ss), blk, 0, stream>>>(mem1, mlp2, g2, be2, nextm);

    // gm = tanh(memory) @ gl_W + gl_b   (direct bf16 MFMA)
    gm_direct<<<dim3(NGg / 64, Ss), blk, 0, stream>>>(tanh16, gl_W, gl_b, gmbuf);

    // gi = gi_mean @ rl_W + rl_b        (direct bf16 MFMA)
    gi_direct<<<dim3(NGg / 64), blk, 0, stream>>>(gim16, rl_W, rl_b, gibuf);

    // final gates + output
    combine_kernel<<<dim3((Bq*Ss*Mm)/256), blk, 0, stream>>>(
        gmbuf, gibuf, nextm, memory, ibp, fbp, out);
}

// Round 19
// 397.647 us; speedup vs baseline: 1.0613x; 1.0613x over previous
//
#include <hip/hip_runtime.h>
#include <hip/hip_bf16.h>

// Problem constants
#define Bq   64
#define Tt   512
#define DIN  512
#define Ss   8
#define HSs  128
#define Hh   8
#define Mm   1024
#define KDd  128
#define NGg  2048

typedef __attribute__((ext_vector_type(8))) short bf16x8;
typedef __attribute__((ext_vector_type(4))) float f32x4;

__device__ __forceinline__ ushort f2b(float f) {
    union { float f; unsigned u; } v; v.f = f;
    unsigned r = v.u + 0x7fffu + ((v.u >> 16) & 1u);   // RNE
    return (ushort)(r >> 16);
}
__device__ __forceinline__ float b2f(ushort b) {
    union { unsigned u; float f; } v; v.u = ((unsigned)b) << 16;
    return v.f;
}
__device__ __forceinline__ float blo(unsigned u) {
    union { unsigned u; float f; } v; v.u = u << 16; return v.f;
}
__device__ __forceinline__ float bhi(unsigned u) {
    union { unsigned u; float f; } v; v.u = u & 0xffff0000u; return v.f;
}

#define GLOAD_LDS16(g, l) __builtin_amdgcn_global_load_lds( \
    (const __attribute__((address_space(1))) void*)(g),     \
    (__attribute__((address_space(3))) void*)(l), 16, 0, 0)

#define LGKM0 do { asm volatile("s_waitcnt lgkmcnt(0)" ::: "memory");         \
                   __builtin_amdgcn_sched_barrier(0); } while (0)

// Shared K-loop body for the 256x256 bf16 MFMA GEMM (r12 gray-code schedule).
#define GEMM_BODY(A_, Bt_, Kdim_)                                             \
    const int NT = (Kdim_) >> 6;                                              \
    const int sr = tid >> 3;                                                  \
    const int sq = (tid & 7) ^ (sr & 7);                                      \
    const ushort* Asrc = (A_)  + (size_t)(row0 + sr) * (Kdim_) + sq * 8;      \
    const ushort* Bsrc = (Bt_) + (size_t)(col0 + sr) * (Kdim_) + sq * 8;      \
    const int ldsw = wid * 1024;                                              \
    auto stage = [&](int isB, int U, int h) {                                 \
        const ushort* s = (isB ? Bsrc : Asrc) + (size_t)h * 128 * (Kdim_)     \
                        + (size_t)U * 64;                                     \
        char* d = lds + (isB ? 65536 : 0) + ((((U) & 1) * 2 + h) << 14) + ldsw;\
        GLOAD_LDS16(s, d);                                                    \
        GLOAD_LDS16(s + (size_t)64 * (Kdim_), d + 8192);                      \
    };                                                                        \
    auto stage_tile = [&](int U) {                                            \
        stage(0, U, 0); stage(0, U, 1); stage(1, U, 0); stage(1, U, 1);       \
    };                                                                        \
    const int l15   = lane & 15;                                              \
    const int s0_16 = (((lane >> 4)) ^ (lane & 7)) << 4;                      \
    const int s1_16 = ((4 + (lane >> 4)) ^ (lane & 7)) << 4;                  \
    const int aoff  = wy * 8192 + l15 * 128;                                  \
    const int boff  = wx * 4096 + l15 * 128;                                  \
    f32x4 acc[4][4][2];                                                       \
    _Pragma("unroll")                                                         \
    for (int p = 0; p < 4; ++p)                                               \
        _Pragma("unroll")                                                     \
        for (int m = 0; m < 4; ++m)                                           \
            _Pragma("unroll")                                                 \
            for (int n = 0; n < 2; ++n) acc[p][m][n] = (f32x4){0.f,0.f,0.f,0.f};\
    stage_tile(0);                                                            \
    stage_tile(1);                                                            \
    asm volatile("s_waitcnt vmcnt(8)" ::: "memory");                          \
    __builtin_amdgcn_s_barrier();                                             \
    asm volatile("" ::: "memory");                                            \
    for (int U = 0; U < NT; ++U) {                                            \
        const char* Ab = lds + ((U & 1) << 15);                               \
        const char* Bb = lds + 65536 + ((U & 1) << 15);                       \
        bf16x8 a0[2][4], a1[2][4];                                            \
        bf16x8 b0[2][2], b1[2][2];                                            \
        _Pragma("unroll")                                                     \
        for (int m = 0; m < 4; ++m) {                                         \
            a0[0][m] = *(const bf16x8*)(Ab + aoff + s0_16 + m * 2048);        \
            a0[1][m] = *(const bf16x8*)(Ab + aoff + s1_16 + m * 2048);        \
        }                                                                     \
        _Pragma("unroll")                                                     \
        for (int n = 0; n < 2; ++n) {                                         \
            b0[0][n] = *(const bf16x8*)(Bb + boff + s0_16 + n * 2048);        \
            b0[1][n] = *(const bf16x8*)(Bb + boff + s1_16 + n * 2048);        \
        }                                                                     \
        LGKM0;                                                                \
        _Pragma("unroll")                                                     \
        for (int m = 0; m < 4; ++m) {                                         \
            a1[0][m] = *(const bf16x8*)(Ab + 16384 + aoff + s0_16 + m * 2048);\
            a1[1][m] = *(const bf16x8*)(Ab + 16384 + aoff + s1_16 + m * 2048);\
        }                                                                     \
        MFMAQ(0, a0, b0);                                                     \
        LGKM0;                                                                \
        _Pragma("unroll")                                                     \
        for (int n = 0; n < 2; ++n) {                                         \
            b1[0][n] = *(const bf16x8*)(Bb + 16384 + boff + s0_16 + n * 2048);\
            b1[1][n] = *(const bf16x8*)(Bb + 16384 + boff + s1_16 + n * 2048);\
        }                                                                     \
        MFMAQ(1, a1, b0);                                                     \
        LGKM0;                                                                \
        __builtin_amdgcn_s_barrier();                                         \
        asm volatile("" ::: "memory");                                        \
        if (U + 2 < NT) stage_tile(U + 2);                                    \
        MFMAQ(3, a1, b1);                                                     \
        MFMAQ(2, a0, b1);                                                     \
        if (U + 2 < NT) asm volatile("s_waitcnt vmcnt(8)" ::: "memory");      \
        else            asm volatile("s_waitcnt vmcnt(0)" ::: "memory");      \
        __builtin_amdgcn_s_barrier();                                         \
        asm volatile("" ::: "memory");                                        \
    }

#define MFMAQ(P, AH, BH)                                                      \
    {                                                                         \
        __builtin_amdgcn_s_setprio(1);                                        \
        _Pragma("unroll")                                                     \
        for (int kk = 0; kk < 2; ++kk)                                        \
            _Pragma("unroll")                                                 \
            for (int m = 0; m < 4; ++m)                                       \
                _Pragma("unroll")                                             \
                for (int n = 0; n < 2; ++n)                                   \
                    acc[P][m][n] = __builtin_amdgcn_mfma_f32_16x16x32_bf16(   \
                        AH[kk][m], BH[kk][n], acc[P][m][n], 0, 0, 0);         \
        __builtin_amdgcn_s_setprio(0);                                        \
    }

// ---------------------------------------------------------------------------
// 256x256 bf16 MFMA GEMM (r12 schedule), standard C epilogue.
// ---------------------------------------------------------------------------
template<int OUT_BF16>
__global__ __launch_bounds__(512)
void gemm_big(const ushort* __restrict__ A, const ushort* __restrict__ Bt,
              const float* __restrict__ bias, void* __restrict__ Cout,
              int ldc, int Kdim)
{
    extern __shared__ __align__(16) char lds[];   // 131072 bytes

    const int tid  = threadIdx.x;
    const int wid  = tid >> 6;
    const int lane = tid & 63;
    const int wy   = wid >> 2;
    const int wx   = wid & 3;

    const int gx   = gridDim.x;
    const int nwg  = gx * gridDim.y;
    const int orig = blockIdx.y * gx + blockIdx.x;
    const int q8   = nwg >> 3, r8 = nwg & 7;
    const int xcd  = orig & 7, idx8 = orig >> 3;
    const int swz  = (xcd < r8 ? xcd * (q8 + 1)
                               : r8 * (q8 + 1) + (xcd - r8) * q8) + idx8;
    const int row0 = (swz / gx) * 256;
    const int col0 = (swz % gx) * 256;

    GEMM_BODY(A, Bt, Kdim)

#pragma unroll
    for (int p = 0; p < 4; ++p) {
        const int rb = row0 + (p & 1) * 128 + wy * 64 + (lane >> 4) * 4;
        const int cb = col0 + (p >> 1) * 128 + wx * 32 + (lane & 15);
#pragma unroll
        for (int n = 0; n < 2; ++n) {
            const float bv = bias[cb + n * 16];
#pragma unroll
            for (int m = 0; m < 4; ++m) {
#pragma unroll
                for (int r = 0; r < 4; ++r) {
                    const float v = acc[p][m][n][r] + bv;
                    const size_t off = (size_t)(rb + m * 16 + r) * ldc + cb + n * 16;
                    if (OUT_BF16) ((ushort*)Cout)[off] = f2b(v);
                    else          ((float*)Cout)[off]  = v;
                }
            }
        }
    }
}

// ---------------------------------------------------------------------------
// gemm_gi: same K-loop; epilogue computes column sums of relu(rl_w*(acc+bp))
// over the block's 256 rows -> partial[row0/256][col]. Deterministic.
// ---------------------------------------------------------------------------
__global__ __launch_bounds__(512)
void gemm_gi(const ushort* __restrict__ A, const ushort* __restrict__ Bt,
             const float* __restrict__ bp, const float* __restrict__ rl_w,
             float* __restrict__ partial, int Kdim)
{
    extern __shared__ __align__(16) char lds[];   // 131072 bytes

    const int tid  = threadIdx.x;
    const int wid  = tid >> 6;
    const int lane = tid & 63;
    const int wy   = wid >> 2;
    const int wx   = wid & 3;

    const int gx   = gridDim.x;
    const int nwg  = gx * gridDim.y;
    const int orig = blockIdx.y * gx + blockIdx.x;
    const int q8   = nwg >> 3, r8 = nwg & 7;
    const int xcd  = orig & 7, idx8 = orig >> 3;
    const int swz  = (xcd < r8 ? xcd * (q8 + 1)
                               : r8 * (q8 + 1) + (xcd - r8) * q8) + idx8;
    const int row0 = (swz / gx) * 256;
    const int col0 = (swz % gx) * 256;

    GEMM_BODY(A, Bt, Kdim)

    float csum[2][2];
#pragma unroll
    for (int ph = 0; ph < 2; ++ph) {
#pragma unroll
        for (int n = 0; n < 2; ++n) {
            const int col = col0 + ph * 128 + wx * 32 + n * 16 + (lane & 15);
            const float bb = bp[col];
            const float w  = rl_w[col];
            float s = 0.f;
#pragma unroll
            for (int rh = 0; rh < 2; ++rh) {
                const int p = ph * 2 + rh;
#pragma unroll
                for (int m = 0; m < 4; ++m)
#pragma unroll
                    for (int r = 0; r < 4; ++r)
                        s += fmaxf(w * (acc[p][m][n][r] + bb), 0.f);
            }
            s += __shfl_xor(s, 16);
            s += __shfl_xor(s, 32);
            csum[ph][n] = s;
        }
    }
    float* redf = (float*)lds;          // [2 wy][256 localcol]
    if ((lane >> 4) == 0) {
#pragma unroll
        for (int ph = 0; ph < 2; ++ph)
#pragma unroll
            for (int n = 0; n < 2; ++n)
                redf[wy * 256 + ph * 128 + wx * 32 + n * 16 + lane] = csum[ph][n];
    }
    __syncthreads();
    if (tid < 256)
        partial[(size_t)(row0 >> 8) * Mm + col0 + tid] = redf[tid] + redf[256 + tid];
}

// gi_finalize: gimean16[b_local][m] = bf16((partial[2b][m]+partial[2b+1][m])/T)
__global__ __launch_bounds__(256)
void gi_finalize(const float* __restrict__ partial, ushort* __restrict__ gimean16)
{
    const int i = blockIdx.x * 256 + threadIdx.x;   // over Bc*Mm
    const int bl = i >> 10, m = i & (Mm - 1);
    const float v = (partial[(size_t)(2 * bl) * Mm + m]
                   + partial[(size_t)(2 * bl + 1) * Mm + m]) * (1.f / (float)Tt);
    gimean16[i] = f2b(v);
}

// ---------------------------------------------------------------------------
// Small 128x128 bf16 MFMA GEMM: BK=32, 4 waves, 64x64/wave, 16 KB LDS.
// ---------------------------------------------------------------------------
template<int OUT_BF16, int RELU>
__global__ __launch_bounds__(256)
void gemm_sm(const ushort* __restrict__ A, const ushort* __restrict__ Bt,
             const float* __restrict__ bias, void* __restrict__ Cout,
             int ldc, int Kdim)
{
    __shared__ __align__(16) ushort As[128 * 32];   // 8 KB
    __shared__ __align__(16) ushort Bs[128 * 32];   // 8 KB

    const int tid  = threadIdx.x;
    const int w    = tid >> 6;
    const int lane = tid & 63;

    const int gx   = gridDim.x;
    const int nwg  = gx * gridDim.y;
    const int orig = blockIdx.y * gx + blockIdx.x;
    const int q8   = nwg >> 3, r8 = nwg & 7;
    const int xcd  = orig & 7, idx8 = orig >> 3;
    const int swz  = (xcd < r8 ? xcd * (q8 + 1)
                               : r8 * (q8 + 1) + (xcd - r8) * q8) + idx8;
    const int row0 = (swz / gx) * 128;
    const int col0 = (swz % gx) * 128;
    const int wr   = w >> 1, wc = w & 1;

    f32x4 acc[4][4];
#pragma unroll
    for (int i = 0; i < 4; ++i)
#pragma unroll
        for (int j = 0; j < 4; ++j) acc[i][j] = (f32x4){0.f, 0.f, 0.f, 0.f};

    const ushort* Ag = A  + (size_t)(row0 + (tid >> 2)) * Kdim + (tid & 3) * 8;
    const ushort* Bg = Bt + (size_t)(col0 + (tid >> 2)) * Kdim + (tid & 3) * 8;

    for (int k0 = 0; k0 < Kdim; k0 += 32) {
        __syncthreads();
#pragma unroll
        for (int is = 0; is < 2; ++is)
            GLOAD_LDS16(Ag + (size_t)is * 64 * Kdim + k0,
                        (char*)As + (is * 256 + w * 64) * 16);
#pragma unroll
        for (int is = 0; is < 2; ++is)
            GLOAD_LDS16(Bg + (size_t)is * 64 * Kdim + k0,
                        (char*)Bs + (is * 256 + w * 64) * 16);
        asm volatile("s_waitcnt vmcnt(0)" ::: "memory");
        __syncthreads();

        bf16x8 a[4], b[4];
#pragma unroll
        for (int i = 0; i < 4; ++i) {
            a[i] = *(const bf16x8*)&As[(wr * 64 + i * 16 + (lane & 15)) * 32 + (lane >> 4) * 8];
            b[i] = *(const bf16x8*)&Bs[(wc * 64 + i * 16 + (lane & 15)) * 32 + (lane >> 4) * 8];
        }
#pragma unroll
        for (int i = 0; i < 4; ++i)
#pragma unroll
            for (int j = 0; j < 4; ++j)
                acc[i][j] = __builtin_amdgcn_mfma_f32_16x16x32_bf16(a[i], b[j], acc[i][j], 0, 0, 0);
    }

    float bsv[4];
#pragma unroll
    for (int j = 0; j < 4; ++j) bsv[j] = bias[col0 + wc * 64 + j * 16 + (lane & 15)];
#pragma unroll
    for (int i = 0; i < 4; ++i) {
        const int row = row0 + wr * 64 + i * 16 + (lane >> 4) * 4;
        const int col = col0 + wc * 64 + (lane & 15);
#pragma unroll
        for (int r = 0; r < 4; ++r) {
            const size_t off = (size_t)(row + r) * ldc + col;
#pragma unroll
            for (int j = 0; j < 4; ++j) {
                float vv = acc[i][j][r] + bsv[j];
                if (RELU) vv = fmaxf(vv, 0.f);
                if (OUT_BF16) ((ushort*)Cout)[off + j * 16] = f2b(vv);
                else          ((float*)Cout)[off + j * 16]  = vv;
            }
        }
    }
}

// ---------------------------------------------------------------------------
// gm_direct: gm[b][s][n] = tanh16[b][s][:] @ gl_W[s][:][n] + gl_b[s][n]
// ---------------------------------------------------------------------------
__global__ __launch_bounds__(256)
void gm_direct(const ushort* __restrict__ tanhA, const float* __restrict__ glW,
               const float* __restrict__ gl_b, float* __restrict__ gm)
{
    const int tid  = threadIdx.x;
    const int w    = tid >> 6;
    const int lane = tid & 63;
    const int s    = blockIdx.y;
    const int n    = blockIdx.x * 64 + w * 16 + (lane & 15);
    const int q8   = (lane >> 4) * 8;

    const float* Bp = glW + (size_t)s * Mm * NGg + n;

    f32x4 acc[4];
#pragma unroll
    for (int i = 0; i < 4; ++i) acc[i] = (f32x4){0.f, 0.f, 0.f, 0.f};

#pragma unroll 2
    for (int k0 = 0; k0 < Mm; k0 += 32) {
        bf16x8 a[4];
#pragma unroll
        for (int i = 0; i < 4; ++i)
            a[i] = *(const bf16x8*)&tanhA[((size_t)(i * 16 + (lane & 15)) * Ss + s) * Mm + k0 + q8];
        bf16x8 bv;
#pragma unroll
        for (int j = 0; j < 8; ++j)
            bv[j] = (short)f2b(Bp[(size_t)(k0 + q8 + j) * NGg]);
#pragma unroll
        for (int i = 0; i < 4; ++i)
            acc[i] = __builtin_amdgcn_mfma_f32_16x16x32_bf16(a[i], bv, acc[i], 0, 0, 0);
    }

    const float bb = gl_b[s * NGg + n];
#pragma unroll
    for (int i = 0; i < 4; ++i) {
#pragma unroll
        for (int r = 0; r < 4; ++r) {
            const int b = i * 16 + (lane >> 4) * 4 + r;
            gm[((size_t)b * Ss + s) * NGg + n] = acc[i][r] + bb;
        }
    }
}

// ---------------------------------------------------------------------------
// gi_direct: gi[b][n] = gimean16[b][:] @ rl_W[:][n] + rl_b[n]  (64 rows)
// ---------------------------------------------------------------------------
__global__ __launch_bounds__(256)
void gi_direct(const ushort* __restrict__ giA, const float* __restrict__ rlW,
               const float* __restrict__ rl_b, float* __restrict__ gi)
{
    const int tid  = threadIdx.x;
    const int w    = tid >> 6;
    const int lane = tid & 63;
    const int n    = blockIdx.x * 64 + w * 16 + (lane & 15);
    const int q8   = (lane >> 4) * 8;

    const float* Bp = rlW + n;

    f32x4 acc[4];
#pragma unroll
    for (int i = 0; i < 4; ++i) acc[i] = (f32x4){0.f, 0.f, 0.f, 0.f};

#pragma unroll 2
    for (int k0 = 0; k0 < Mm; k0 += 32) {
        bf16x8 a[4];
#pragma unroll
        for (int i = 0; i < 4; ++i)
            a[i] = *(const bf16x8*)&giA[(size_t)(i * 16 + (lane & 15)) * Mm + k0 + q8];
        bf16x8 bv;
#pragma unroll
        for (int j = 0; j < 8; ++j)
            bv[j] = (short)f2b(Bp[(size_t)(k0 + q8 + j) * NGg]);
#pragma unroll
        for (int i = 0; i < 4; ++i)
            acc[i] = __builtin_amdgcn_mfma_f32_16x16x32_bf16(a[i], bv, acc[i], 0, 0, 0);
    }

    const float bb = rl_b[n];
#pragma unroll
    for (int i = 0; i < 4; ++i) {
#pragma unroll
        for (int r = 0; r < 4; ++r) {
            const int b = i * 16 + (lane >> 4) * 4 + r;
            gi[(size_t)b * NGg + n] = acc[i][r] + bb;
        }
    }
}

// ---------------------------------------------------------------------------
__global__ __launch_bounds__(256)
void transpose_to_bf16(const float* __restrict__ in, ushort* __restrict__ out,
                       int R, int C)
{
    __shared__ float t[32][33];
    const int c0 = blockIdx.x * 32, r0 = blockIdx.y * 32;
    const int tx = threadIdx.x & 31, ty = threadIdx.x >> 5;   // 32 x 8
#pragma unroll
    for (int i = 0; i < 32; i += 8)
        t[ty + i][tx] = in[(size_t)(r0 + ty + i) * C + c0 + tx];
    __syncthreads();
#pragma unroll
    for (int i = 0; i < 32; i += 8)
        out[(size_t)(c0 + ty + i) * R + r0 + tx] = f2b(t[tx][ty + i]);
}

// 4x 1024x1024 transposes in one launch (blockIdx.z selects the matrix)
__global__ __launch_bounds__(256)
void transpose4_to_bf16(const float* __restrict__ s0, const float* __restrict__ s1,
                        const float* __restrict__ s2, const float* __restrict__ s3,
                        ushort* __restrict__ d0, ushort* __restrict__ d1,
                        ushort* __restrict__ d2, ushort* __restrict__ d3)
{
    const float* in; ushort* out;
    switch (blockIdx.z) {
        case 0:  in = s0; out = d0; break;
        case 1:  in = s1; out = d1; break;
        case 2:  in = s2; out = d2; break;
        default: in = s3; out = d3; break;
    }
    __shared__ float t[32][33];
    const int c0 = blockIdx.x * 32, r0 = blockIdx.y * 32;
    const int tx = threadIdx.x & 31, ty = threadIdx.x >> 5;
#pragma unroll
    for (int i = 0; i < 32; i += 8)
        t[ty + i][tx] = in[(size_t)(r0 + ty + i) * Mm + c0 + tx];
    __syncthreads();
#pragma unroll
    for (int i = 0; i < 32; i += 8)
        out[(size_t)(c0 + ty + i) * Mm + r0 + tx] = f2b(t[tx][ty + i]);
}

__global__ __launch_bounds__(256)
void conv_bf16(const float* __restrict__ in, ushort* __restrict__ out)
{
    const int i = blockIdx.x * 256 + threadIdx.x;
    float4 v = ((const float4*)in)[i];
    ushort4 o;
    o.x = f2b(v.x); o.y = f2b(v.y); o.z = f2b(v.z); o.w = f2b(v.w);
    ((ushort4*)out)[i] = o;
}

// memory -> bf16(memory) and bf16(tanh(memory)) in one pass
__global__ __launch_bounds__(256)
void mem_tanh_bf16(const float* __restrict__ in, ushort* __restrict__ o1,
                   ushort* __restrict__ o2)
{
    const int i = blockIdx.x * 256 + threadIdx.x;
    float4 v = ((const float4*)in)[i];
    ushort4 a, b;
    a.x = f2b(v.x); a.y = f2b(v.y); a.z = f2b(v.z); a.w = f2b(v.w);
    b.x = f2b(tanhf(v.x)); b.y = f2b(tanhf(v.y));
    b.z = f2b(tanhf(v.z)); b.w = f2b(tanhf(v.w));
    ((ushort4*)o1)[i] = a;
    ((ushort4*)o2)[i] = b;
}

__global__ __launch_bounds__(256)
void fill0(float* __restrict__ o)
{
    o[blockIdx.x * 256 + threadIdx.x] = 0.f;
}

// ---------------------------------------------------------------------------
// fuse_bias: outb[n] = sum_m bp[m] * Wkv[m][n] + bkv[n], n in [0, 2048).
// ---------------------------------------------------------------------------
__global__ __launch_bounds__(256)
void fuse_bias(const float* __restrict__ bp,
               const float* __restrict__ Wk, const float* __restrict__ Wv,
               const float* __restrict__ bk, const float* __restrict__ bv,
               float* __restrict__ outb)
{
    __shared__ float red[4][64];
    const int col = threadIdx.x & 63;
    const int mq  = threadIdx.x >> 6;
    const int n   = blockIdx.x * 64 + col;
    const float* W = (n < Mm) ? Wk : Wv;
    const int nn   = n & (Mm - 1);
    float s = 0.f;
    for (int m = mq * 256; m < mq * 256 + 256; ++m)
        s += bp[m] * W[(size_t)m * Mm + nn];
    red[mq][col] = s;
    __syncthreads();
    if (mq == 0) {
        float t = red[0][col] + red[1][col] + red[2][col] + red[3][col];
        outb[n] = t + ((n < Mm) ? bk[nn] : bv[nn]);
    }
}

// ---------------------------------------------------------------------------
// Fused attention per (b, h), 512 threads (8 waves). q fp32; kv bf16 [.,T,2M].
// ---------------------------------------------------------------------------
__global__ __launch_bounds__(512)
void attn_kernel(const float* __restrict__ q, const ushort* __restrict__ kv,
                 float* __restrict__ att)
{
    const int b = blockIdx.x / Hh;
    const int h = blockIdx.x % Hh;
    const int tid = threadIdx.x;

    __shared__ float qs[Ss][KDd];     // 4 KB
    __shared__ float sc[Ss][Tt];      // 16 KB

    {
        const int idx = tid * 2;
        const int s = idx >> 7;
        const int d = idx & 127;
        float2 qv = *(const float2*)&q[((size_t)(b * Ss + s)) * Mm + h * KDd + d];
        qs[s][d] = qv.x; qs[s][d + 1] = qv.y;
    }
    __syncthreads();

    {
        const int t = tid;
        const ushort* kr = kv + ((size_t)(b * Tt + t)) * (2 * Mm) + h * KDd;
        float acc[Ss];
#pragma unroll
        for (int s = 0; s < Ss; ++s) acc[s] = 0.f;
        for (int d = 0; d < KDd; d += 8) {
            uint4 u = *(const uint4*)(kr + d);
            float k0 = blo(u.x), k1 = bhi(u.x), k2 = blo(u.y), k3 = bhi(u.y);
            float k4 = blo(u.z), k5 = bhi(u.z), k6 = blo(u.w), k7 = bhi(u.w);
#pragma unroll
            for (int s = 0; s < Ss; ++s)
                acc[s] += qs[s][d + 0] * k0 + qs[s][d + 1] * k1
                        + qs[s][d + 2] * k2 + qs[s][d + 3] * k3
                        + qs[s][d + 4] * k4 + qs[s][d + 5] * k5
                        + qs[s][d + 6] * k6 + qs[s][d + 7] * k7;
        }
#pragma unroll
        for (int s = 0; s < Ss; ++s) sc[s][t] = acc[s];
    }
    __syncthreads();

    const int s    = tid >> 6;
    const int lane = tid & 63;
    float mx = -1e30f;
    for (int t = lane; t < Tt; t += 64) mx = fmaxf(mx, sc[s][t]);
#pragma unroll
    for (int m = 32; m >= 1; m >>= 1) mx = fmaxf(mx, __shfl_xor(mx, m));
    float sum = 0.f;
    for (int t = lane; t < Tt; t += 64) {
        float e = __expf(sc[s][t] - mx);
        sc[s][t] = e;
        sum += e;
    }
#pragma unroll
    for (int m = 32; m >= 1; m >>= 1) sum += __shfl_xor(sum, m);
    const float inv = 1.f / sum;

    const int d0 = lane * 2;
    const ushort* vb = kv + ((size_t)(b * Tt)) * (2 * Mm) + Mm + h * KDd + d0;
    float ax = 0.f, ay = 0.f;
    for (int t = 0; t < Tt; ++t) {
        const float p = sc[s][t];
        const unsigned u = *(const unsigned*)(vb + (size_t)t * (2 * Mm));
        ax = fmaf(p, blo(u), ax);
        ay = fmaf(p, bhi(u), ay);
    }
    float2 o = make_float2(ax * inv, ay * inv);
    *(float2*)&att[((size_t)(b * Ss + s)) * Mm + h * KDd + d0] = o;
}

// ---------------------------------------------------------------------------
__global__ __launch_bounds__(256)
void ln_add(const float* __restrict__ a, const float* __restrict__ b,
            const float* __restrict__ g, const float* __restrict__ be,
            float* __restrict__ out)
{
    const int row = blockIdx.x;
    const int tid = threadIdx.x;
    const float* ap = a + (size_t)row * Mm;
    const float* bp = b + (size_t)row * Mm;

    float4 av = *(const float4*)&ap[tid * 4];
    float4 bv = *(const float4*)&bp[tid * 4];
    float x0 = av.x + bv.x, x1 = av.y + bv.y, x2 = av.z + bv.z, x3 = av.w + bv.w;
    float s  = x0 + x1 + x2 + x3;
    float ss = x0 * x0 + x1 * x1 + x2 * x2 + x3 * x3;
#pragma unroll
    for (int m = 32; m >= 1; m >>= 1) {
        s  += __shfl_xor(s, m);
        ss += __shfl_xor(ss, m);
    }
    __shared__ float red[2][4];
    const int wid = tid >> 6;
    if ((tid & 63) == 0) { red[0][wid] = s; red[1][wid] = ss; }
    __syncthreads();
    s  = red[0][0] + red[0][1] + red[0][2] + red[0][3];
    ss = red[1][0] + red[1][1] + red[1][2] + red[1][3];
    const float mu  = s * (1.f / (float)Mm);
    const float var = ss * (1.f / (float)Mm) - mu * mu;
    const float inv = rsqrtf(var + 1e-5f);

    float4 gv = *(const float4*)&g[tid * 4];
    float4 bev = *(const float4*)&be[tid * 4];
    float4 o;
    o.x = (x0 - mu) * inv * gv.x + bev.x;
    o.y = (x1 - mu) * inv * gv.y + bev.y;
    o.z = (x2 - mu) * inv * gv.z + bev.z;
    o.w = (x3 - mu) * inv * gv.w + bev.w;
    *(float4*)&out[(size_t)row * Mm + tid * 4] = o;
}

__global__ __launch_bounds__(256)
void combine_kernel(const float* __restrict__ gm, const float* __restrict__ gi,
                    const float* __restrict__ nextm, const float* __restrict__ memory,
                    const float* __restrict__ ibp, const float* __restrict__ fbp,
                    float* __restrict__ out)
{
    const int idx = blockIdx.x * 256 + threadIdx.x;
    const int m  = idx & (Mm - 1);
    const int bs = idx >> 10;
    const int b  = bs >> 3;
    const float ib = ibp[0], fb = fbp[0];
    const float gmi = gm[(size_t)bs * NGg + m];
    const float gmf = gm[(size_t)bs * NGg + Mm + m];
    const float gii = gi[(size_t)b * NGg + m];
    const float gif = gi[(size_t)b * NGg + Mm + m];
    const float ig = 1.f / (1.f + __expf(-(gmi + gii + ib)));
    const float fg = 1.f / (1.f + __expf(-(gmf + gif + fb)));
    out[idx] = ig * tanhf(nextm[idx]) + fg * memory[idx];
}

// ---------------------------------------------------------------------------
extern "C" void kernel_launch(void* const* d_in, const int* in_sizes, int n_in,
                              void* d_out, int out_size, void* d_ws, size_t ws_size,
                              hipStream_t stream)
{
    const float* inputs = (const float*)d_in[0];
    const float* memory = (const float*)d_in[1];
    const float* Wp  = (const float*)d_in[2];
    const float* bp  = (const float*)d_in[3];
    const float* Wq  = (const float*)d_in[4];
    const float* bq  = (const float*)d_in[5];
    const float* Wk  = (const float*)d_in[6];
    const float* bk  = (const float*)d_in[7];
    const float* Wv  = (const float*)d_in[8];
    const float* bv  = (const float*)d_in[9];
    const float* Wm  = (const float*)d_in[10];
    const float* bm  = (const float*)d_in[11];
    const float* g1  = (const float*)d_in[12];
    const float* be1 = (const float*)d_in[13];
    const float* g2  = (const float*)d_in[14];
    const float* be2 = (const float*)d_in[15];
    const float* rl_w = (const float*)d_in[16];
    const float* rl_W = (const float*)d_in[17];
    const float* rl_b = (const float*)d_in[18];
    const float* gl_W = (const float*)d_in[19];
    const float* gl_b = (const float*)d_in[20];
    const float* ibp  = (const float*)d_in[21];
    const float* fbp  = (const float*)d_in[22];
    float* out = (float*)d_out;

    // allow 128 KiB dynamic LDS for the big MFMA GEMMs
    (void)hipFuncSetAttribute(reinterpret_cast<const void*>(&gemm_big<1>),
                              hipFuncAttributeMaxDynamicSharedMemorySize, 131072);
    (void)hipFuncSetAttribute(reinterpret_cast<const void*>(&gemm_gi),
                              hipFuncAttributeMaxDynamicSharedMemorySize, 131072);

    // ---- workspace layout (float units) ----
    const size_t N_SM = (size_t)Bq * Ss * Mm;     // 524,288
    float* ws = (float*)d_ws;
    float* qbuf   = ws;
    float* attb   = qbuf   + N_SM;
    float* mem1   = attb   + N_SM;
    float* mlp2   = mem1   + N_SM;
    float* nextm  = mlp2   + N_SM;
    float* gibuf  = nextm  + N_SM;                        // [64][NGg]
    float* gmbuf  = gibuf  + (size_t)Bq * NGg;
    float* gipart = gmbuf  + (size_t)Bq * Ss * NGg;       // [<=128][Mm] partials
    float* bkvf   = gipart + (size_t)128 * Mm;            // [2048] fused bias
    float* bz     = bkvf + NGg;                           // [512] zeros
    float* pconst = bz + 512;
    // bf16 constants + small bf16 activations
    ushort* ib16  = (ushort*)pconst;                      // [B*T][DIN]
    ushort* WpT   = ib16  + (size_t)Bq * Tt * DIN;        // [M][DIN]
    ushort* WkvT  = WpT   + (size_t)Mm * DIN;             // [2M][M]
    ushort* WqT   = WkvT  + (size_t)2 * Mm * Mm;          // [M][M]
    ushort* WmT   = WqT   + (size_t)Mm * Mm;              // [M][M]
    ushort* mem16 = WmT   + (size_t)Mm * Mm;              // [B*S][M]
    ushort* m116  = mem16 + N_SM;                         // bf16(mem1)
    ushort* mlp116= m116  + N_SM;                         // bf16(relu(mlp1))
    ushort* Wp16  = mlp116 + N_SM;                        // [DIN][M] bf16(Wp)
    ushort* WpkvT = Wp16  + (size_t)DIN * Mm;             // [2M][DIN]
    ushort* tanh16= WpkvT + (size_t)2 * Mm * DIN;         // [B*S][M]
    ushort* gim16 = tanh16 + N_SM;                        // [64][M] bf16(gi_mean)
    ushort* cend  = gim16 + (size_t)Bq * Mm;
    // chunk region start (float*, 16B aligned)
    size_t const_u16 = (size_t)(cend - (ushort*)pconst);
    size_t const_floats = (size_t)(pconst - ws) + (const_u16 + 1) / 2;
    const_floats = (const_floats + 3) & ~(size_t)3;       // 16B align
    float* cstart = ws + const_floats;

    // per-chunk: kv bf16 ([Bc*T][2M] u16 = Bc*Tt*Mm floats).
    // CAP Bc AT 32: at Bc=64 the 128 MB kv chunk is evicted from L3 between
    // the GEMM write and the attention read (r18: attn FETCH 295 MB, 109 us);
    // at Bc=32 the 64 MB chunk stays L3-warm (r15: 33 MB FETCH, ~2x faster).
    int Bc = 32;
    while (Bc > 1 &&
           (const_floats + (size_t)Bc * Tt * Mm) * sizeof(float) > ws_size)
        Bc >>= 1;
    ushort* kvb16 = (ushort*)cstart;                      // [Bc*T][2M]

    const dim3 blk(256);

    // ---- precompute bf16 operands + fused weights/bias ----
    conv_bf16<<<dim3((Bq * Tt * DIN) / 1024), blk, 0, stream>>>(inputs, ib16);
    mem_tanh_bf16<<<dim3((Bq * Ss * Mm) / 1024), blk, 0, stream>>>(memory, mem16, tanh16);
    conv_bf16<<<dim3((DIN * Mm) / 1024), blk, 0, stream>>>(Wp, Wp16);
    transpose_to_bf16<<<dim3(Mm / 32, DIN / 32), blk, 0, stream>>>(Wp, WpT, DIN, Mm);
    transpose4_to_bf16<<<dim3(Mm / 32, Mm / 32, 4), blk, 0, stream>>>(
        Wk, Wv, Wq, Wm, WkvT, WkvT + (size_t)Mm * Mm, WqT, WmT);
    fill0<<<dim3(2), blk, 0, stream>>>(bz);

    // WpkvT[n][d] = sum_m WkvT[n][m] * Wp16[d][m]  (= (Wp@Wkv)^T, bf16)
    gemm_sm<1,0><<<dim3(DIN/128, (2*Mm)/128), blk, 0, stream>>>(
        WkvT, Wp16, bz, WpkvT, DIN, Mm);

    // bkvf[n] = bp @ Wkv[:,n] + [bk|bv][n]   (fp32, deterministic)
    fuse_bias<<<dim3(NGg / 64), blk, 0, stream>>>(bp, Wk, Wv, bk, bv, bkvf);

    // q = memory @ Wq + bq   (128^2 MFMA, fp32 out)
    gemm_sm<0,0><<<dim3(Mm/128, (Bq*Ss)/128), blk, 0, stream>>>(
        mem16, WqT, bq, qbuf, Mm, Mm);

    // ---- chunked: kv (fused, K=512), gi (fused epilogue), attention ----
    for (int c0 = 0; c0 < Bq; c0 += Bc) {
        const int rows = Bc * Tt;

        // kv = bf16(inputs_c @ Wpkv + bkvf)   (N=2048, K=512)
        gemm_big<1><<<dim3((2*Mm)/256, rows/256), dim3(512), 131072, stream>>>(
            ib16 + (size_t)c0 * Tt * DIN, WpkvT, bkvf, kvb16, 2*Mm, DIN);

        // gi partials: column sums of relu(rl_w*(inputs_c@Wp + bp))
        gemm_gi<<<dim3(Mm/256, rows/256), dim3(512), 131072, stream>>>(
            ib16 + (size_t)c0 * Tt * DIN, WpT, bp, rl_w, gipart, DIN);
        gi_finalize<<<dim3((Bc * Mm) / 256), blk, 0, stream>>>(
            gipart, gim16 + (size_t)c0 * Mm);

        // attention for this chunk (512-thread blocks)
        attn_kernel<<<dim3(Bc * Hh), dim3(512), 0, stream>>>(
            qbuf + (size_t)c0 * Ss * Mm, kvb16,
            attb + (size_t)c0 * Ss * Mm);
    }

    // mem1 = LN(memory + att) ; then bf16 copy for the MLP GEMMs
    ln_add<<<dim3(Bq * Ss), blk, 0, stream>>>(memory, attb, g1, be1, mem1);
    conv_bf16<<<dim3((Bq * Ss * Mm) / 1024), blk, 0, stream>>>(mem1, m116);

    // mlp1 = relu(mem1 @ Wm + bm)  -> bf16 ; mlp2 = relu(mlp1 @ Wm + bm) -> fp32
    gemm_sm<1,1><<<dim3(Mm/128, (Bq*Ss)/128), blk, 0, stream>>>(
        m116, WmT, bm, mlp116, Mm, Mm);
    gemm_sm<0,1><<<dim3(Mm/128, (Bq*Ss)/128), blk, 0, stream>>>(
        mlp116, WmT, bm, mlp2, Mm, Mm);

    // next = LN(mem1 + mlp2)
    ln_add<<<dim3(Bq * Ss), blk, 0, stream>>>(mem1, mlp2, g2, be2, nextm);

    // gm = tanh(memory) @ gl_W + gl_b   (direct bf16 MFMA)
    gm_direct<<<dim3(NGg / 64, Ss), blk, 0, stream>>>(tanh16, gl_W, gl_b, gmbuf);

    // gi = gi_mean @ rl_W + rl_b        (direct bf16 MFMA)
    gi_direct<<<dim3(NGg / 64), blk, 0, stream>>>(gim16, rl_W, rl_b, gibuf);

    // final gates + output
    combine_kernel<<<dim3((Bq*Ss*Mm)/256), blk, 0, stream>>>(
        gmbuf, gibuf, nextm, memory, ibp, fbp, out);
}